// Round 3
// baseline (717.252 us; speedup 1.0000x reference)
//
#include <hip/hip_runtime.h>
#include <math.h>

#define NB 16
#define SL 2048
#define HD 64
#define TQ 16
#define BK 64
#define NT (SL / BK)          // 32 k-tiles
#define SC2 0.18033688f       // (1/TEMPERATURE) * log2(e): exp(s/8) = exp2(s*SC2)
#define SSTRIDE 2056          // fp16 elems per S row (2048 + 8 pad, 16B-aligned rows)

typedef _Float16 half8 __attribute__((ext_vector_type(8)));
typedef float floatx4 __attribute__((ext_vector_type(4)));
typedef int intx4 __attribute__((ext_vector_type(4)));

__device__ __forceinline__ half8 load_frag_f32(const float* p) {
  floatx4 f0 = *(const floatx4*)p;
  floatx4 f1 = *(const floatx4*)(p + 4);
  half8 h;
  h[0] = (_Float16)f0[0]; h[1] = (_Float16)f0[1];
  h[2] = (_Float16)f0[2]; h[3] = (_Float16)f0[3];
  h[4] = (_Float16)f1[0]; h[5] = (_Float16)f1[1];
  h[6] = (_Float16)f1[2]; h[7] = (_Float16)f1[3];
  return h;
}

// Fused pre-pass, 256 threads/block.
// bid < 512  : prep — K -> KH (f16), V -> VT (f16 transposed [b][d][k]).
// bid >= 512 : pack — reads DM+MMk (537 MB, the only consumer of the raw masks),
//              combines keep = dm & ~mk, bit-packs to BITS (8 MiB, L2/L3-resident).
// (prep-first ordering fixes the round-2 MODE-1 fallback bug: grid=512 -> prep only.)
__global__ __launch_bounds__(256) void prep_pack_kernel(
    const float* __restrict__ K, const float* __restrict__ V,
    const int* __restrict__ DM, const int* __restrict__ MMk,
    _Float16* __restrict__ KH, _Float16* __restrict__ VT,
    unsigned char* __restrict__ BITS)
{
  const int bid = blockIdx.x;
  const int t   = (int)threadIdx.x;

  if (bid >= 512) {
    // ---- pack: 16 rows per block, thread t covers cols [t*8, t*8+8) ----
    const size_t r0 = (size_t)(bid - 512) * 16;
    #pragma unroll 4
    for (int r = 0; r < 16; ++r) {
      const size_t off = (r0 + r) * SL + (size_t)t * 8;
      intx4 d0 = __builtin_nontemporal_load((const intx4*)(DM + off));
      intx4 d1 = __builtin_nontemporal_load((const intx4*)(DM + off + 4));
      intx4 m0 = __builtin_nontemporal_load((const intx4*)(MMk + off));
      intx4 m1 = __builtin_nontemporal_load((const intx4*)(MMk + off + 4));
      unsigned byte = 0;
      #pragma unroll
      for (int j = 0; j < 4; ++j) {
        byte |= (unsigned)((d0[j] & ~m0[j]) & 1) << j;
        byte |= (unsigned)((d1[j] & ~m1[j]) & 1) << (j + 4);
      }
      BITS[(r0 + r) * (SL / 8) + t] = (unsigned char)byte;   // regular store: L2/L3
    }
    return;
  }

  // ---- prep: K/V conversion, block handles 64 k-rows of one batch ----
  __shared__ __align__(16) _Float16 tile[64][72];   // V tile, 16-chunk XOR swizzle
  const int k0 = (bid & 31) * 64;
  const int b  = bid >> 5;
  const size_t base = (size_t)b * SL * HD;
  const int r  = t >> 2;
  const int cq = (t & 3) * 16;

  const float* kp = K + base + (size_t)(k0 + r) * HD + cq;
  const float* vp = V + base + (size_t)(k0 + r) * HD + cq;
  half8 kh0 = load_frag_f32(kp), kh1 = load_frag_f32(kp + 8);
  half8 vh0 = load_frag_f32(vp), vh1 = load_frag_f32(vp + 8);

  _Float16* khp = KH + base + (size_t)(k0 + r) * HD + cq;
  *(half8*)khp       = kh0;
  *(half8*)(khp + 8) = kh1;

  const int wc = cq ^ (((r >> 4) & 3) * 16);
  *(half8*)&tile[r][wc]     = vh0;
  *(half8*)&tile[r][wc + 8] = vh1;
  __syncthreads();

  const int sx = ((cq >> 4) & 3) * 16;
  half8 o0, o1;
  #pragma unroll
  for (int i = 0; i < 8; ++i) {
    o0[i] = tile[cq + i][r ^ sx];
    o1[i] = tile[cq + 8 + i][r ^ sx];
  }
  _Float16* vt = VT + (size_t)b * HD * SL + (size_t)r * SL + k0 + cq;
  *(half8*)vt       = o0;
  *(half8*)(vt + 8) = o1;
}

// One block = 16 q-rows of one batch, 512 threads = 8 waves, 2 blocks/CU.
// MODE 2 (primary): packed mask bits preloaded to LDS (4 KB/block); masking + exp2 +
//   row-sum FUSED into Phase A (P1 pass eliminated — round-3 change). exp2 runs on the
//   f32 MFMA accumulator under the K-load/MFMA latency; per-lane partial row sums are
//   shuffle-reduced then combined via a tiny LDS table.
// MODE 1: f16 K/V, masks from global (round-2 structure with separate P1).
// MODE 0: no workspace at all.
template <int MODE>
__global__ __launch_bounds__(512, 4) void attn_kernel(
    const float* __restrict__ Q, const float* __restrict__ K,
    const float* __restrict__ V, const _Float16* __restrict__ KH,
    const _Float16* __restrict__ VT, const unsigned char* __restrict__ BITS,
    const int* __restrict__ DM, const int* __restrict__ MMk,
    float* __restrict__ Out, float* __restrict__ Attn)
{
  const int qt    = blockIdx.x;
  const int b     = blockIdx.y;
  const int tid   = (int)threadIdx.x;
  const int w     = tid >> 6;
  const int w4    = w & 3;
  const int hf    = w >> 2;
  const int lane  = tid & 63;
  const int quad  = lane >> 4;
  const int nl    = lane & 15;
  const int row16 = tid >> 5;
  const int ci    = tid & 31;

  const int qbase    = qt * TQ;
  const size_t bLD   = (size_t)b * SL * HD;
  const size_t mbase = ((size_t)b * SL + qbase) * SL;

  __shared__ __align__(16) _Float16 S[TQ * SSTRIDE];        // 65.8 KB
  __shared__ __align__(8) unsigned char bitsRM[TQ][264];    // 4.2 KB, row stride 264 for bank spread
  __shared__ float sinv_s[TQ];
  __shared__ float partial[TQ][9];
  __shared__ float obuf[TQ][65];

  // ---- bits preload: one u64/thread -> LDS row-major [row][256B] (stride 264)
  if constexpr (MODE == 2) {
    const unsigned long long* browp =
        (const unsigned long long*)BITS + ((size_t)b * SL + qbase) * (SL / 64);
    const unsigned long long wbits = browp[tid];   // row tid>>5, bytes (tid&31)*8..+8
    *(unsigned long long*)&bitsRM[tid >> 5][(tid & 31) * 8] = wbits;
  }

  // ---- Q fragments (A operand): lane holds Q[qbase + nl][quad*8+j (+32)]
  half8 aq0, aq1;
  {
    const float* qp = Q + bLD + (size_t)(qbase + nl) * HD + quad * 8;
    aq0 = load_frag_f32(qp);
    aq1 = load_frag_f32(qp + 32);
  }
  if constexpr (MODE == 2) __syncthreads();   // bitsRM visible before Phase A

  // ========== Phase A: QK^T (+ fused mask/exp2/rowsum in MODE 2) ==========
  const int kt0 = hf * (NT / 2);
  float rsum[4] = {0.f, 0.f, 0.f, 0.f};
  #pragma unroll 2
  for (int kti = 0; kti < NT / 2; ++kti) {
    const int kt = kt0 + kti;
    half8 bk0, bk1;
    if constexpr (MODE >= 1) {
      const _Float16* kp = KH + bLD + (size_t)(kt * BK + w4 * 16 + nl) * HD + quad * 8;
      bk0 = *(const half8*)kp;
      bk1 = *(const half8*)(kp + 32);
    } else {
      const float* kp = K + bLD + (size_t)(kt * BK + w4 * 16 + nl) * HD + quad * 8;
      bk0 = load_frag_f32(kp);
      bk1 = load_frag_f32(kp + 32);
    }
    floatx4 acc = {0.f, 0.f, 0.f, 0.f};
    acc = __builtin_amdgcn_mfma_f32_16x16x32_f16(aq0, bk0, acc, 0, 0, 0);
    acc = __builtin_amdgcn_mfma_f32_16x16x32_f16(aq1, bk1, acc, 0, 0, 0);
    const int col = kt * BK + w4 * 16 + nl;
    if constexpr (MODE == 2) {
      // mask bits for (row=quad*4+r, cols w4*16..+15 of tile kt): one broadcast u16/row
      const unsigned char* bp = &bitsRM[0][0] + (quad * 4) * 264 + kt * 8 + w4 * 2;
      #pragma unroll
      for (int r = 0; r < 4; ++r) {
        const unsigned short mb = *(const unsigned short*)(bp + r * 264);
        const float e = ((mb >> nl) & 1)
                            ? __builtin_amdgcn_exp2f(acc[r] * SC2) : 0.f;
        S[(quad * 4 + r) * SSTRIDE + col] = (_Float16)e;   // e <= ~e^6, fp16 safe
        rsum[r] += e;
      }
    } else {
      #pragma unroll
      for (int r = 0; r < 4; ++r)
        S[(quad * 4 + r) * SSTRIDE + col] = (_Float16)(acc[r] * SC2);
    }
  }

  if constexpr (MODE == 2) {
    // reduce rsum over the 16 nl-lanes of each quad group
    #pragma unroll
    for (int r = 0; r < 4; ++r) {
      float v = rsum[r];
      v += __shfl_xor(v, 1, 64);
      v += __shfl_xor(v, 2, 64);
      v += __shfl_xor(v, 4, 64);
      v += __shfl_xor(v, 8, 64);
      rsum[r] = v;
    }
    if (nl == 0) {
      #pragma unroll
      for (int r = 0; r < 4; ++r) partial[quad * 4 + r][w] = rsum[r];
    }
    __syncthreads();   // S (e values) + partial visible
    if (tid < 16) {
      float s = 0.f;
      #pragma unroll
      for (int wi = 0; wi < 8; ++wi) s += partial[tid][wi];
      sinv_s[tid] = (s > 0.f) ? 1.f / s : 0.f;
    }
    __syncthreads();   // sinv_s visible
  } else {
    __syncthreads();
    // ---- P1 (fallback): global masks + exp2 + sum, one in-place pass ----
    _Float16* srow0 = &S[row16 * SSTRIDE];
    const int* dmr = DM  + mbase + (size_t)row16 * SL;
    const int* mkr = MMk + mbase + (size_t)row16 * SL;
    float sum = 0.f;
    #pragma unroll 4
    for (int it = 0; it < 8; ++it) {
      const int c = it * 256 + ci * 8;
      intx4 d0 = __builtin_nontemporal_load((const intx4*)(dmr + c));
      intx4 d1 = __builtin_nontemporal_load((const intx4*)(dmr + c + 4));
      intx4 m0 = __builtin_nontemporal_load((const intx4*)(mkr + c));
      intx4 m1 = __builtin_nontemporal_load((const intx4*)(mkr + c + 4));
      half8 s8 = *(const half8*)(srow0 + c);
      half8 e8;
      #pragma unroll
      for (int j = 0; j < 4; ++j) {
        const int keep0 = d0[j] & ~m0[j];
        const int keep1 = d1[j] & ~m1[j];
        const float e0 = keep0 ? __builtin_amdgcn_exp2f((float)s8[j])     : 0.f;
        const float e1 = keep1 ? __builtin_amdgcn_exp2f((float)s8[j + 4]) : 0.f;
        sum += e0 + e1;
        e8[j]     = (_Float16)e0;
        e8[j + 4] = (_Float16)e1;
      }
      *(half8*)(srow0 + c) = e8;
    }
    #pragma unroll
    for (int off = 1; off < 32; off <<= 1)
      sum += __shfl_xor(sum, off, 64);
    const float is = (sum > 0.f) ? 1.f / sum : 0.f;
    if (ci == 0) sinv_s[row16] = is;
    __syncthreads();
  }

  // ===== PV MFMA (16 tiles/wave) with interleaved normalized attn stores =====
  const float isr = sinv_s[row16];
  _Float16* srow = &S[row16 * SSTRIDE];
  float* arow = Attn + mbase + (size_t)row16 * SL;
  floatx4 oacc = {0.f, 0.f, 0.f, 0.f};
  #pragma unroll
  for (int kti = 0; kti < NT / 2; ++kti) {
    const int kt = kt0 + kti;
    // A operand: lane holds E[m = nl][k = kt*64 + quad*8 + j (+32)]
    half8 ap0 = *(const half8*)(&S[nl * SSTRIDE + kt * BK + quad * 8]);
    half8 ap1 = *(const half8*)(&S[nl * SSTRIDE + kt * BK + quad * 8 + 32]);
    // B operand: lane holds V[k = kt*64 + quad*8 + j (+32)][n = w4*16 + nl]
    half8 bv0, bv1;
    if constexpr (MODE >= 1) {
      const _Float16* vp = VT + bLD + (size_t)(w4 * 16 + nl) * SL + kt * BK + quad * 8;
      bv0 = *(const half8*)vp;
      bv1 = *(const half8*)(vp + 32);
    } else {
      const float* vp = V + bLD + (size_t)(kt * BK + quad * 8) * HD + w4 * 16 + nl;
      #pragma unroll
      for (int j = 0; j < 8; ++j) {
        bv0[j] = (_Float16)vp[(size_t)j * HD];
        bv1[j] = (_Float16)vp[(size_t)(j + 32) * HD];
      }
    }
    oacc = __builtin_amdgcn_mfma_f32_16x16x32_f16(ap0, bv0, oacc, 0, 0, 0);
    oacc = __builtin_amdgcn_mfma_f32_16x16x32_f16(ap1, bv1, oacc, 0, 0, 0);
    // normalized attn store chunk every other tile: drains under MFMA latency
    if ((kti & 1) == 0) {
      const int c = (kti >> 1) * 256 + ci * 8;
      half8 e8v = *(const half8*)(srow + c);
      floatx4 o0, o1;
      #pragma unroll
      for (int j = 0; j < 4; ++j) {
        o0[j] = (float)e8v[j]     * isr;
        o1[j] = (float)e8v[j + 4] * isr;
      }
      __builtin_nontemporal_store(o0, (floatx4*)(arow + c));
      __builtin_nontemporal_store(o1, (floatx4*)(arow + c + 4));
    }
  }

  // ---- merge the two k-halves, normalize, store O
  if (hf == 1) {
    #pragma unroll
    for (int r = 0; r < 4; ++r)
      obuf[quad * 4 + r][w4 * 16 + nl] = oacc[r];
  }
  __syncthreads();
  if (hf == 0) {
    float* op = Out + ((size_t)b * SL + qbase) * HD;
    #pragma unroll
    for (int r = 0; r < 4; ++r) {
      const int row = quad * 4 + r;
      op[(size_t)row * HD + w4 * 16 + nl] =
          (oacc[r] + obuf[row][w4 * 16 + nl]) * sinv_s[row];
    }
  }
}

extern "C" void kernel_launch(void* const* d_in, const int* in_sizes, int n_in,
                              void* d_out, int out_size, void* d_ws, size_t ws_size,
                              hipStream_t stream) {
  const float* Q  = (const float*)d_in[0];
  const float* K  = (const float*)d_in[1];
  const float* V  = (const float*)d_in[2];
  const int* DM   = (const int*)d_in[3];
  const int* MMk  = (const int*)d_in[4];
  float* Out  = (float*)d_out;
  float* Attn = (float*)d_out + (size_t)NB * SL * HD;
  dim3 grid(SL / TQ, NB);

  const size_t needKV   = (size_t)2 * NB * SL * HD * sizeof(_Float16);  // 8 MiB
  const size_t needBits = (size_t)NB * SL * (SL / 8);                   // 8 MiB
  if (d_ws != nullptr && ws_size >= needKV + needBits) {
    _Float16* KH = (_Float16*)d_ws;
    _Float16* VT = KH + (size_t)NB * SL * HD;
    unsigned char* BITS = (unsigned char*)(VT + (size_t)NB * SL * HD);
    prep_pack_kernel<<<dim3(512 + 2048), 256, 0, stream>>>(K, V, DM, MMk, KH, VT, BITS);
    attn_kernel<2><<<grid, 512, 0, stream>>>(Q, K, V, KH, VT, BITS, DM, MMk, Out, Attn);
  } else if (d_ws != nullptr && ws_size >= needKV) {
    _Float16* KH = (_Float16*)d_ws;
    _Float16* VT = KH + (size_t)NB * SL * HD;
    prep_pack_kernel<<<dim3(512), 256, 0, stream>>>(K, V, DM, MMk, KH, VT, nullptr);
    attn_kernel<1><<<grid, 512, 0, stream>>>(Q, K, V, KH, VT, nullptr, DM, MMk, Out, Attn);
  } else {
    attn_kernel<0><<<grid, 512, 0, stream>>>(Q, K, V, nullptr, nullptr, nullptr, DM, MMk, Out, Attn);
  }
}